// Round 2
// baseline (357.346 us; speedup 1.0000x reference)
//
#include <hip/hip_runtime.h>
#include <math.h>

#define FREQ_DIM 256
#define TDIM 512
#define MODC 352
#define EPS 1e-5f

__device__ __forceinline__ float silu_f(float x) {
    return x / (1.0f + expf(-x));
}

// emb[b, j] = cos(t[b]*freq[j])  (j<128)  |  sin(t[b]*freq[j-128])  (j>=128)
__global__ void k_emb(const float* __restrict__ t, float* __restrict__ emb) {
    int b = blockIdx.x;
    int j = threadIdx.x;            // 256 threads
    float tv = t[b];
    const float lm = 9.210340371976184f;   // ln(10000)
    int h = j & 127;
    float freq = expf(-lm * (float)h * (1.0f / 128.0f));
    float arg = tv * freq;
    emb[b * FREQ_DIM + j] = (j < 128) ? cosf(arg) : sinf(arg);
}

// out[r, j] = act( in[r, :K] @ w[:K, j] + bias[j] ), 8 rows per block.
template <int K, int NC, bool PRE_SILU, bool POST_SILU>
__global__ __launch_bounds__(256) void k_gemm(const float* __restrict__ in,
                                              const float* __restrict__ w,
                                              const float* __restrict__ bias,
                                              float* __restrict__ out) {
    __shared__ float s_in[8][K];
    int row0 = blockIdx.x * 8;
    for (int idx = threadIdx.x; idx < 8 * K; idx += 256) {
        int r = idx / K, k = idx - r * K;
        float v = in[(row0 + r) * K + k];
        if (PRE_SILU) v = silu_f(v);
        s_in[r][k] = v;
    }
    __syncthreads();
    for (int j = threadIdx.x; j < NC; j += 256) {
        float acc[8] = {0, 0, 0, 0, 0, 0, 0, 0};
        for (int k = 0; k < K; ++k) {
            float wv = w[k * NC + j];
#pragma unroll
            for (int r = 0; r < 8; ++r) acc[r] += s_in[r][k] * wv;
        }
        float bv = bias[j];
#pragma unroll
        for (int r = 0; r < 8; ++r) {
            float o = acc[r] + bv;
            if (POST_SILU) o = silu_f(o);
            out[(row0 + r) * NC + j] = o;
        }
    }
}

// One wave (64 lanes) per node. Row = 480 f32 = 120 float4.
// float4 idx:  0..31 -> seg0 (layernorm, floats 0..127)
//             32..79 -> seg1 (floats 128..319, 192 elems)
//             80..119-> seg2 (floats 320..479, 160 elems)
__global__ __launch_bounds__(256) void k_main(const float* __restrict__ x,
                                              const int* __restrict__ batch,
                                              const float* __restrict__ mod,
                                              float* __restrict__ out, int N) {
    int node = blockIdx.x * 4 + (threadIdx.x >> 6);
    if (node >= N) return;
    int lane = threadIdx.x & 63;

    const float4* rp = (const float4*)(x + (size_t)node * 480);
    float4 a = rp[lane];                         // f4 idx lane (0..63)
    float4 c = make_float4(0.f, 0.f, 0.f, 0.f);
    if (lane < 56) c = rp[64 + lane];            // f4 idx 64..119

    float s0 = 0.f, q0 = 0.f, q1 = 0.f, q2 = 0.f;
    float da = a.x * a.x + a.y * a.y + a.z * a.z + a.w * a.w;
    if (lane < 32) { s0 = a.x + a.y + a.z + a.w; q0 = da; }
    else           { q1 = da; }
    float dc = c.x * c.x + c.y * c.y + c.z * c.z + c.w * c.w;
    if (lane < 16)      q1 += dc;
    else if (lane < 56) q2 = dc;

#pragma unroll
    for (int m = 1; m < 64; m <<= 1) {
        s0 += __shfl_xor(s0, m, 64);
        q0 += __shfl_xor(q0, m, 64);
        q1 += __shfl_xor(q1, m, 64);
        q2 += __shfl_xor(q2, m, 64);
    }

    int b = batch[node];
    const float* mrow = mod + (size_t)b * MODC;
    float4 m4 = *(const float4*)mrow;            // cols 0..3 (need 0,1,2)

    float mean = s0 * (1.0f / 128.0f);
    float var  = q0 * (1.0f / 128.0f) - mean * mean;
    float r0 = rsqrtf(var + EPS) * (1.0f + m4.x);
    float r1 = rsqrtf(q1 * (1.0f / 192.0f) + EPS) * (1.0f + m4.y);
    float r2 = rsqrtf(q2 * (1.0f / 160.0f) + EPS) * (1.0f + m4.z);

    float4* op = (float4*)(out + (size_t)node * 480);
    float4 o;
    if (lane < 32) {
        // shift = mod[b, 224 + 4*lane .. +3]; base offset 224 f32 is 16B aligned
        float4 sh = *(const float4*)(mrow + 224 + 4 * lane);
        o.x = (a.x - mean) * r0 + sh.x;
        o.y = (a.y - mean) * r0 + sh.y;
        o.z = (a.z - mean) * r0 + sh.z;
        o.w = (a.w - mean) * r0 + sh.w;
    } else {
        o.x = a.x * r1; o.y = a.y * r1; o.z = a.z * r1; o.w = a.w * r1;
    }
    op[lane] = o;
    if (lane < 56) {
        float rr = (lane < 16) ? r1 : r2;
        float4 o2;
        o2.x = c.x * rr; o2.y = c.y * rr; o2.z = c.z * rr; o2.w = c.w * rr;
        op[64 + lane] = o2;
    }
}

extern "C" void kernel_launch(void* const* d_in, const int* in_sizes, int n_in,
                              void* d_out, int out_size, void* d_ws, size_t ws_size,
                              hipStream_t stream) {
    const float* node_input = (const float*)d_in[0];
    const float* t          = (const float*)d_in[1];
    const int*   batch      = (const int*)d_in[2];
    const float* w1         = (const float*)d_in[3];
    const float* b1         = (const float*)d_in[4];
    const float* w2         = (const float*)d_in[5];
    const float* b2         = (const float*)d_in[6];
    const float* wm         = (const float*)d_in[7];
    const float* bm         = (const float*)d_in[8];
    float* out = (float*)d_out;

    int N = in_sizes[0] / 480;   // 100000
    int B = in_sizes[1];         // 1024

    float* ws  = (float*)d_ws;
    float* emb = ws;                        // B*256
    float* h1  = emb + (size_t)B * FREQ_DIM; // B*512
    float* t2  = h1 + (size_t)B * TDIM;      // B*512
    float* mb  = t2 + (size_t)B * TDIM;      // B*352

    k_emb<<<B, 256, 0, stream>>>(t, emb);
    k_gemm<FREQ_DIM, TDIM, false, true ><<<B / 8, 256, 0, stream>>>(emb, w1, b1, h1);
    k_gemm<TDIM,     TDIM, false, false><<<B / 8, 256, 0, stream>>>(h1, w2, b2, t2);
    k_gemm<TDIM,     MODC, true,  false><<<B / 8, 256, 0, stream>>>(t2, wm, bm, mb);
    k_main<<<(N + 3) / 4, 256, 0, stream>>>(node_input, batch, mb, out, N);
}

// Round 3
// 130.091 us; speedup vs baseline: 2.7469x; 2.7469x over previous
//
#include <hip/hip_runtime.h>
#include <math.h>

#define FREQ_DIM 256
#define TDIM 512
#define MODC 352
#define EPS 1e-5f

__device__ __forceinline__ float silu_f(float x) {
    return x / (1.0f + expf(-x));
}

// emb[b, j] = cos(t[b]*freq[j])  (j<128)  |  sin(t[b]*freq[j-128])  (j>=128)
__global__ void k_emb(const float* __restrict__ t, float* __restrict__ emb) {
    int b = blockIdx.x;
    int j = threadIdx.x;            // 256 threads
    float tv = t[b];
    const float lm = 9.210340371976184f;   // ln(10000)
    int h = j & 127;
    float freq = expf(-lm * (float)h * (1.0f / 128.0f));
    float arg = tv * freq;
    emb[b * FREQ_DIM + j] = (j < 128) ? cosf(arg) : sinf(arg);
}

// out[r, j] = act( in[r, :K] @ w[:K, j] + bias[j] )
// Tiling: 8 rows x 128 cols per block; 256 threads = 4 k-slices (one per wave)
// x 64 lanes; each lane owns cols (cp, cp+64) -> 8x2 accumulators.
template <int K, int NC, bool PRE_SILU, bool POST_SILU>
__global__ __launch_bounds__(256) void k_gemm(const float* __restrict__ in,
                                              const float* __restrict__ w,
                                              const float* __restrict__ bias,
                                              float* __restrict__ out) {
    constexpr int C = 128;
    constexpr int KS = 4;
    constexpr int KC = K / KS;
    constexpr int NCB = (NC + C - 1) / C;

    __shared__ float s_in[8][K];          // <= 16 KB
    __shared__ float s_acc[KS][8][C];     // 16 KB

    int rowgrp = blockIdx.x / NCB;
    int colgrp = blockIdx.x % NCB;
    int row0 = rowgrp * 8;
    int col0 = colgrp * C;

    // Stage 8 input rows into LDS (vectorized, optional pre-silu).
    for (int idx = threadIdx.x; idx < 8 * K / 4; idx += 256) {
        int r = idx / (K / 4), k4 = idx - r * (K / 4);
        float4 v = *(const float4*)(in + (size_t)(row0 + r) * K + k4 * 4);
        if (PRE_SILU) {
            v.x = silu_f(v.x); v.y = silu_f(v.y);
            v.z = silu_f(v.z); v.w = silu_f(v.w);
        }
        *(float4*)&s_in[r][k4 * 4] = v;
    }
    __syncthreads();

    int ks = threadIdx.x >> 6;      // wave id: k-slice
    int cp = threadIdx.x & 63;      // lane: column
    int j0 = col0 + cp;
    int j1 = j0 + 64;
    // clamp (NC=352 tail): compute garbage on clamped cols, never stored
    int jj0 = j0 < NC ? j0 : NC - 1;
    int jj1 = j1 < NC ? j1 : NC - 1;

    float acc0[8] = {0, 0, 0, 0, 0, 0, 0, 0};
    float acc1[8] = {0, 0, 0, 0, 0, 0, 0, 0};

    for (int k = ks * KC; k < (ks + 1) * KC; k += 4) {
        float4 a[8];
#pragma unroll
        for (int r = 0; r < 8; ++r) a[r] = *(const float4*)&s_in[r][k];
#pragma unroll
        for (int kk = 0; kk < 4; ++kk) {
            float wv0 = w[(size_t)(k + kk) * NC + jj0];
            float wv1 = w[(size_t)(k + kk) * NC + jj1];
#pragma unroll
            for (int r = 0; r < 8; ++r) {
                float av = ((const float*)&a[r])[kk];
                acc0[r] += av * wv0;
                acc1[r] += av * wv1;
            }
        }
    }

#pragma unroll
    for (int r = 0; r < 8; ++r) {
        s_acc[ks][r][cp] = acc0[r];
        s_acc[ks][r][cp + 64] = acc1[r];
    }
    __syncthreads();

    // Reduce 4 k-slices; 8*C outputs, 256 threads -> 4 each.
    for (int o = threadIdx.x; o < 8 * C; o += 256) {
        int r = o / C, c = o - r * C;
        int j = col0 + c;
        if (j < NC) {
            float v = s_acc[0][r][c] + s_acc[1][r][c] + s_acc[2][r][c] + s_acc[3][r][c];
            v += bias[j];
            if (POST_SILU) v = silu_f(v);
            out[(size_t)(row0 + r) * NC + j] = v;
        }
    }
}

// One wave (64 lanes) per node. Row = 480 f32 = 120 float4.
__global__ __launch_bounds__(256) void k_main(const float* __restrict__ x,
                                              const int* __restrict__ batch,
                                              const float* __restrict__ mod,
                                              float* __restrict__ out, int N) {
    int node = blockIdx.x * 4 + (threadIdx.x >> 6);
    if (node >= N) return;
    int lane = threadIdx.x & 63;

    const float4* rp = (const float4*)(x + (size_t)node * 480);
    float4 a = rp[lane];                         // f4 idx lane (0..63)
    float4 c = make_float4(0.f, 0.f, 0.f, 0.f);
    if (lane < 56) c = rp[64 + lane];            // f4 idx 64..119

    float s0 = 0.f, q0 = 0.f, q1 = 0.f, q2 = 0.f;
    float da = a.x * a.x + a.y * a.y + a.z * a.z + a.w * a.w;
    if (lane < 32) { s0 = a.x + a.y + a.z + a.w; q0 = da; }
    else           { q1 = da; }
    float dc = c.x * c.x + c.y * c.y + c.z * c.z + c.w * c.w;
    if (lane < 16)      q1 += dc;
    else if (lane < 56) q2 = dc;

#pragma unroll
    for (int m = 1; m < 64; m <<= 1) {
        s0 += __shfl_xor(s0, m, 64);
        q0 += __shfl_xor(q0, m, 64);
        q1 += __shfl_xor(q1, m, 64);
        q2 += __shfl_xor(q2, m, 64);
    }

    int b = batch[node];
    const float* mrow = mod + (size_t)b * MODC;
    float4 m4 = *(const float4*)mrow;            // cols 0..3 (need 0,1,2)

    float mean = s0 * (1.0f / 128.0f);
    float var  = q0 * (1.0f / 128.0f) - mean * mean;
    float r0 = rsqrtf(var + EPS) * (1.0f + m4.x);
    float r1 = rsqrtf(q1 * (1.0f / 192.0f) + EPS) * (1.0f + m4.y);
    float r2 = rsqrtf(q2 * (1.0f / 160.0f) + EPS) * (1.0f + m4.z);

    float4* op = (float4*)(out + (size_t)node * 480);
    float4 o;
    if (lane < 32) {
        float4 sh = *(const float4*)(mrow + 224 + 4 * lane);
        o.x = (a.x - mean) * r0 + sh.x;
        o.y = (a.y - mean) * r0 + sh.y;
        o.z = (a.z - mean) * r0 + sh.z;
        o.w = (a.w - mean) * r0 + sh.w;
    } else {
        o.x = a.x * r1; o.y = a.y * r1; o.z = a.z * r1; o.w = a.w * r1;
    }
    op[lane] = o;
    if (lane < 56) {
        float rr = (lane < 16) ? r1 : r2;
        float4 o2;
        o2.x = c.x * rr; o2.y = c.y * rr; o2.z = c.z * rr; o2.w = c.w * rr;
        op[64 + lane] = o2;
    }
}

extern "C" void kernel_launch(void* const* d_in, const int* in_sizes, int n_in,
                              void* d_out, int out_size, void* d_ws, size_t ws_size,
                              hipStream_t stream) {
    const float* node_input = (const float*)d_in[0];
    const float* t          = (const float*)d_in[1];
    const int*   batch      = (const int*)d_in[2];
    const float* w1         = (const float*)d_in[3];
    const float* b1         = (const float*)d_in[4];
    const float* w2         = (const float*)d_in[5];
    const float* b2         = (const float*)d_in[6];
    const float* wm         = (const float*)d_in[7];
    const float* bm         = (const float*)d_in[8];
    float* out = (float*)d_out;

    int N = in_sizes[0] / 480;   // 100000
    int B = in_sizes[1];         // 1024

    float* ws  = (float*)d_ws;
    float* emb = ws;                         // B*256
    float* h1  = emb + (size_t)B * FREQ_DIM; // B*512
    float* t2  = h1 + (size_t)B * TDIM;      // B*512
    float* mb  = t2 + (size_t)B * TDIM;      // B*352

    k_emb<<<B, 256, 0, stream>>>(t, emb);
    k_gemm<FREQ_DIM, TDIM, false, true ><<<(B / 8) * 4, 256, 0, stream>>>(emb, w1, b1, h1);
    k_gemm<TDIM,     TDIM, false, false><<<(B / 8) * 4, 256, 0, stream>>>(h1, w2, b2, t2);
    k_gemm<TDIM,     MODC, true,  false><<<(B / 8) * 3, 256, 0, stream>>>(t2, wm, bm, mb);
    k_main<<<(N + 3) / 4, 256, 0, stream>>>(node_input, batch, mb, out, N);
}